// Round 15
// baseline (187.141 us; speedup 1.0000x reference)
//
#include <hip/hip_runtime.h>

typedef short short8 __attribute__((ext_vector_type(8)));
typedef float f32x4  __attribute__((ext_vector_type(4)));

namespace {
constexpr int B_  = 4;
constexpr int C_  = 256;
constexpr int H_  = 80;
constexpr int W1_ = 184;
constexpr int W2_ = 184;
constexpr int G_  = 2;
constexpr int S_  = 9;
constexpr int CH  = 72;              // 4 levels * 2 gaussians * 9 samples
constexpr int TM  = 64;              // w1 rows per block
constexpr int HW1 = H_ * W1_;
constexpr int HW2 = H_ * W2_;
constexpr int NK  = 4;               // K chunks of 64 (C=256): halve barrier-drain events vs KC=32
// LDS byte map (staging, 64 KB exactly; rows are 64 bf16 = 128 B):
//   A_hi[64][64]  @ 0       (8 KB)   A_lo @ 8192
//   B_hi[192][64] @ 16384  (24 KB)   B_lo @ 40960
// slot swizzle: 16B slot s (k/8) stored at s ^ (row&7)  -> 2-way bank alias on read & write (free)
// epilogue reuse: corrS[16][192] f32 @ 0, pyr[16][161] f32 @ float-idx 3072
}

struct HL { short hi, lo; };

// fp32 -> bf16 hi/lo split, RNE both terms. Residual after hi+lo ~ 2^-18 |x|.
__device__ __forceinline__ HL bsplit(float x) {
    HL r_;
    unsigned u = __builtin_bit_cast(unsigned, x);
    unsigned r = (u + 0x7fffu + ((u >> 16) & 1u)) & 0xffff0000u;
    r_.hi = (short)(r >> 16);
    float lof = x - __builtin_bit_cast(float, r);     // exact in fp32
    unsigned ul = __builtin_bit_cast(unsigned, lof);
    r_.lo = (short)((ul + 0x7fffu + ((ul >> 16) & 1u)) >> 16);
    return r_;
}

__global__ __launch_bounds__(256, 2)
void corr1d_mfma(const float* __restrict__ fmap1, const float* __restrict__ fmap2,
                 const float* __restrict__ coords, const float* __restrict__ sigma,
                 float* __restrict__ out)
{
    __shared__ __align__(16) char ldsRaw[65536];
    float* ldsF = (float*)ldsRaw;

    const int tile   = blockIdx.x;            // 0..2
    const int bh     = blockIdx.y;            // 0..319
    const int b      = bh / H_;
    const int h      = bh - b * H_;
    const int w1base = tile * TM;

    const int tid = threadIdx.x;
    const int l   = tid & 63;
    const int w   = __builtin_amdgcn_readfirstlane(tid >> 6);  // wave id, SGPR
    const int lm  = l & 15;
    const int kg  = l >> 4;

    const int am = 16 * w + lm;               // wave w owns m-tile w (A row for fragments)

    // ---- global load columns (clamped in-bounds; garbage rows/cols never consumed) ----
    const int mcol  = min(w1base + l, W1_ - 1);   // tile 2 rows >=56 garbage, masked at out-store
    const int ncol0 = l;
    const int ncol1 = 64 + l;
    const int ncol2 = min(128 + l, W2_ - 1);      // B rows 184..191 garbage, never consumed
    const int kb0   = b * C_ + 16 * w;            // + kc*64 + j -> fmap row (k index)

    // single register staging set: 64 floats/thread (16 A + 3x16 B) -- depth-1 (R9-proven)
    float aS[16], bS0[16], bS1[16], bS2[16];

    // issue 64 dword loads for chunk kc_ (thread: fixed columns, 16 consecutive k = its k-range)
#define LOADCHUNK(kc_) do {                                                        \
        const float* aB = fmap1 + ((size_t)(kb0 + (kc_) * 64) * H_ + h) * W1_;     \
        const float* bB = fmap2 + ((size_t)(kb0 + (kc_) * 64) * H_ + h) * W2_;     \
        _Pragma("unroll")                                                          \
        for (int j = 0; j < 16; ++j) {                                             \
            aS[j]  = aB[j * HW1 + mcol];                                           \
            bS0[j] = bB[j * HW2 + ncol0];                                          \
            bS1[j] = bB[j * HW2 + ncol1];                                          \
            bS2[j] = bB[j * HW2 + ncol2];                                          \
        }                                                                          \
    } while (0)

    // convert staged regs to bf16 hi/lo and ds_write_b128 into slot-swizzled LDS.
    // thread covers k-slots s = 2*w + c (c=0,1) of rows l (A) and l,64+l,128+l (B);
    // (64+l)&7 == (128+l)&7 == l&7, so one swizzled slot serves all four rows.
#define CONVWRITE do {                                                             \
        _Pragma("unroll")                                                          \
        for (int c = 0; c < 2; ++c) {                                              \
            const int sw = (((2 * w + c) ^ (l & 7)) << 4);                         \
            short8 vh, vl;                                                         \
            _Pragma("unroll") for (int j = 0; j < 8; ++j) { HL t = bsplit(aS[c*8+j]);  vh[j] = t.hi; vl[j] = t.lo; } \
            *(short8*)(ldsRaw + l * 128 + sw) = vh;                                \
            *(short8*)(ldsRaw + 8192 + l * 128 + sw) = vl;                         \
            _Pragma("unroll") for (int j = 0; j < 8; ++j) { HL t = bsplit(bS0[c*8+j]); vh[j] = t.hi; vl[j] = t.lo; } \
            *(short8*)(ldsRaw + 16384 + l * 128 + sw) = vh;                        \
            *(short8*)(ldsRaw + 40960 + l * 128 + sw) = vl;                        \
            _Pragma("unroll") for (int j = 0; j < 8; ++j) { HL t = bsplit(bS1[c*8+j]); vh[j] = t.hi; vl[j] = t.lo; } \
            *(short8*)(ldsRaw + 16384 + 8192 + l * 128 + sw) = vh;                 \
            *(short8*)(ldsRaw + 40960 + 8192 + l * 128 + sw) = vl;                 \
            _Pragma("unroll") for (int j = 0; j < 8; ++j) { HL t = bsplit(bS2[c*8+j]); vh[j] = t.hi; vl[j] = t.lo; } \
            *(short8*)(ldsRaw + 16384 + 16384 + l * 128 + sw) = vh;                \
            *(short8*)(ldsRaw + 40960 + 16384 + l * 128 + sw) = vl;                \
        }                                                                          \
    } while (0)

    f32x4 acc[12];
    #pragma unroll
    for (int nt = 0; nt < 12; ++nt) acc[nt] = (f32x4)(0.f);

    // 3-pass bf16-split MFMA over one staged chunk (two k-steps of 32):
    // D += Ahi*Bhi + Ahi*Blo + Alo*Bhi
#define COMPUTE do {                                                               \
        _Pragma("unroll")                                                          \
        for (int t = 0; t < 2; ++t) {                                              \
            const int sa = (((t * 4 + kg) ^ (am & 7)) << 4);                       \
            const short8 ah = *(const short8*)(ldsRaw + am * 128 + sa);            \
            const short8 al = *(const short8*)(ldsRaw + 8192 + am * 128 + sa);     \
            _Pragma("unroll")                                                      \
            for (int nt = 0; nt < 12; ++nt) {                                      \
                const int n  = nt * 16 + lm;                                       \
                const int sb = (((t * 4 + kg) ^ (n & 7)) << 4);                    \
                const short8 bh = *(const short8*)(ldsRaw + 16384 + n * 128 + sb); \
                const short8 bl = *(const short8*)(ldsRaw + 40960 + n * 128 + sb); \
                acc[nt] = __builtin_amdgcn_mfma_f32_16x16x32_bf16(ah, bh, acc[nt], 0, 0, 0); \
                acc[nt] = __builtin_amdgcn_mfma_f32_16x16x32_bf16(ah, bl, acc[nt], 0, 0, 0); \
                acc[nt] = __builtin_amdgcn_mfma_f32_16x16x32_bf16(al, bh, acc[nt], 0, 0, 0); \
            }                                                                      \
        }                                                                          \
    } while (0)

    // ---- K pipeline: depth-1 issue-early staging, single LDS buffer, 2 barriers/chunk, 4 chunks ----
    LOADCHUNK(0);
    CONVWRITE;
    __syncthreads();
    #pragma unroll 1
    for (int kc = 0; kc < NK; ++kc) {
        if (kc < NK - 1) LOADCHUNK(kc + 1);   // in flight across COMPUTE (drained at the barrier)
        COMPUTE;
        __syncthreads();                      // all waves done reading this chunk
        if (kc < NK - 1) {
            CONVWRITE;
            __syncthreads();                  // writes visible
        }
    }

    // ---- fused epilogue: 4 chunks of 16 rows (wave q owns chunk q's corr rows) ----
    float* corrS = ldsF;                      // [16][192]
    float* pyr   = ldsF + 3072;               // [16][161]: lvl1[92] lvl2[46] lvl3[23]
    constexpr float scale = 0.0625f;          // 1/sqrt(256)

    for (int q = 0; q < 4; ++q) {
        if (w == q) {
            // D layout (m89-verified): col = lane&15, row = (lane>>4)*4 + reg
            #pragma unroll
            for (int nt = 0; nt < 12; ++nt)
                #pragma unroll
                for (int r = 0; r < 4; ++r)
                    corrS[(kg * 4 + r) * 192 + nt * 16 + lm] = acc[nt][r] * scale;
        }
        __syncthreads();

        // pooled pyramid levels (direct from level0)
        for (int e = tid; e < 16 * 161; e += 256) {
            const int rI = e / 161;
            const int p  = e - rI * 161;
            const float* row = corrS + rI * 192;
            float v;
            if (p < 92) {
                const int j = 2 * p;
                v = 0.5f * (row[j] + row[j + 1]);
            } else if (p < 138) {
                const int j = (p - 92) * 4;
                v = 0.25f * (row[j] + row[j + 1] + row[j + 2] + row[j + 3]);
            } else {
                const int j = (p - 138) * 8;
                v = 0.125f * (row[j] + row[j+1] + row[j+2] + row[j+3]
                             + row[j+4] + row[j+5] + row[j+6] + row[j+7]);
            }
            pyr[rI * 161 + p] = v;
        }
        __syncthreads();

        // Gaussian sampling: 72 channels x 16 rows; 16 consecutive lanes share a channel
        for (int t = tid; t < CH * 16; t += 256) {
            const int ch = t >> 4;
            const int r  = t & 15;
            const int w1 = w1base + q * 16 + r;
            if (w1 < W1_) {
                const int lvl = ch / (G_ * S_);
                const int rem = ch - lvl * (G_ * S_);
                const int g   = rem / S_;
                const int s   = rem - g * S_;
                const int cix = ((b * G_ + g) * H_ + h) * W1_ + w1;
                const float x  = (float)(s - S_ / 2) * sigma[cix] + coords[cix];
                const float xi = x * (1.0f / (float)(1 << lvl));
                const int   Wl = W2_ >> lvl;
                const float x0 = floorf(xi);
                const float wr = xi - x0;
                const int i0 = (int)x0;
                const int i1 = i0 + 1;
                const float* rowp = (lvl == 0) ? (corrS + r * 192)
                                  : (pyr + r * 161 + ((lvl == 1) ? 0 : (lvl == 2) ? 92 : 138));
                const int i0c = min(max(i0, 0), Wl - 1);
                const int i1c = min(max(i1, 0), Wl - 1);
                const float v0 = (i0 >= 0 && i0 < Wl) ? rowp[i0c] : 0.f;
                const float v1 = (i1 >= 0 && i1 < Wl) ? rowp[i1c] : 0.f;
                out[((b * CH + ch) * H_ + h) * W1_ + w1] = (1.f - wr) * v0 + wr * v1;
            }
        }
        __syncthreads();
    }
#undef LOADCHUNK
#undef CONVWRITE
#undef COMPUTE
}

extern "C" void kernel_launch(void* const* d_in, const int* in_sizes, int n_in,
                              void* d_out, int out_size, void* d_ws, size_t ws_size,
                              hipStream_t stream) {
    const float* fmap1  = (const float*)d_in[0];
    const float* fmap2  = (const float*)d_in[1];
    const float* coords = (const float*)d_in[2];
    const float* sigma  = (const float*)d_in[3];
    float* out = (float*)d_out;

    dim3 grid((W1_ + TM - 1) / TM, B_ * H_);   // 3 x 320
    corr1d_mfma<<<grid, 256, 0, stream>>>(fmap1, fmap2, coords, sigma, out);
}